// Round 12
// baseline (243.221 us; speedup 1.0000x reference)
//
#include <hip/hip_runtime.h>
#include <math.h>
#include <float.h>

#define BATCH 16
#define SEQ 96
#define NNODE 256
#define CFREQ 9
#define MNODE (NNODE * CFREQ)      // 2304
#define BM (BATCH * MNODE)         // 36864
#define KNN 8
#define EMBED 128
#define HIDDEN 64
#define TN (SEQ * NNODE)           // 24576
#define KCAP 64
#define NBLK (BM / 256)            // 144 scan blocks
#define HROWS 16                   // head rows per block (1024 threads)
#define FEW (CFREQ * EMBED)        // 1152 fe outputs

__constant__ float COS16[16] = {
    1.0f, 0.9238795325112867f, 0.7071067811865476f, 0.3826834323650898f,
    0.0f, -0.3826834323650898f, -0.7071067811865476f, -0.9238795325112867f,
    -1.0f, -0.9238795325112867f, -0.7071067811865476f, -0.3826834323650898f,
    0.0f, 0.3826834323650898f, 0.7071067811865476f, 0.9238795325112867f};
__constant__ float SIN16[16] = {
    0.0f, 0.3826834323650898f, 0.7071067811865476f, 0.9238795325112867f,
    1.0f, 0.9238795325112867f, 0.7071067811865476f, 0.3826834323650898f,
    0.0f, -0.3826834323650898f, -0.7071067811865476f, -0.9238795325112867f,
    -1.0f, -0.9238795325112867f, -0.7071067811865476f, -0.3826834323650898f};

static __device__ __forceinline__ float silu_f(float x) {
    return x / (1.0f + expf(-x));
}

// ranking value h = |fj|^2 - 2*(fi . fj) (monotone with d = sqi + h)
static __device__ __forceinline__ float rank_h(float2 fj, float xi2, float yi2) {
    float sqj = __fmaf_rn(fj.y, fj.y, __fmul_rn(fj.x, fj.x));
    return __fmaf_rn(xi2, fj.x, __fmaf_rn(yi2, fj.y, sqj));
}

// Fused: per-(b,n,c) thread computes trend inline (bit-exact expression) and
// the rfft16 bin; zeroes cnt and the scan ticket. Extra blocks compute FE.
__global__ void __launch_bounds__(256) prep_kernel(
    const float* __restrict__ x, float* __restrict__ S, int* __restrict__ cnt,
    const float* __restrict__ femb, const float* __restrict__ Wr,
    const float* __restrict__ Wi, float* __restrict__ FE, int* __restrict__ gtotal) {
    int gid = blockIdx.x * 256 + threadIdx.x;
    if (gid < BM) {
        if (gid == 0) *gtotal = 0;
        cnt[gid] = 0;
        int b = gid / MNODE;
        int m = gid - b * MNODE;
        int n = m / CFREQ;
        int c = m - n * CFREQ;
        const float* xb = x + b * TN + n;
        float xv[17];
        #pragma unroll
        for (int t = 0; t < 17; ++t) xv[t] = xb[t * NNODE];
        float re = 0.0f, im = 0.0f;
        #pragma unroll
        for (int t = 0; t < 16; ++t) {
            int tm = t > 0 ? t - 1 : 0;
            float tr = (xv[tm] + xv[t] + xv[t + 1]) * (1.0f / 3.0f);
            float s = xv[t] - tr;
            int k = (c * t) & 15;
            re += s * COS16[k];
            im -= s * SIN16[k];
        }
        S[gid * 2 + 0] = re * 0.25f;
        S[gid * 2 + 1] = im * 0.25f;
    } else {
        int f = gid - BM;
        if (f < FEW) {
            int c = f / EMBED;
            int e = f - c * EMBED;
            float ar = 0.0f, ai = 0.0f;
            for (int k = 0; k < EMBED; ++k) {
                float fv = femb[c * EMBED + k];
                ar += fv * Wr[e * EMBED + k];
                ai += fv * Wi[e * EMBED + k];
            }
            FE[f * 2 + 0] = ar;
            FE[f * 2 + 1] = ai;
        }
    }
}

// One WAVE per row, 4 rows per 256-block. Exact top-8.
//  P1: h[36] cached in regs; per-lane min.
//  T : max over 8 disjoint 8-lane groups of group-min of lane minima.
//  P2: ballot/popcll-prefix append of survivor u64 keys into wave-private
//      LDS buffer (round-9-proven form; the mbcnt variant scheduled worse
//      and cost ~4us -- reverted).
//  P3 (guarded: KNN <= total <= KCAP): pad to multiple of 8 with SENT,
//      8-wide rank selection via 4x ds_read_b128.
//  Else: exact fallback from the h cache (insert network + 8-round merge).
__global__ void __launch_bounds__(256, 8) knn_kernel(const float* __restrict__ S,
                                                     int* __restrict__ idx, int* __restrict__ cnt) {
    __shared__ float2 f[MNODE];                        // 18432 B
    __shared__ unsigned long long kbuf[4][KCAP];       // 2048 B -> total 20480 = 160K/8
    int b = blockIdx.y;
    int tid = threadIdx.x;
    for (int t = tid; t < MNODE; t += 256) {
        f[t] = make_float2(S[(b * MNODE + t) * 2 + 0], S[(b * MNODE + t) * 2 + 1]);
    }
    __syncthreads();
    int wave = tid >> 6, lane = tid & 63;
    int i = blockIdx.x * 4 + wave;
    float2 fi = f[i];
    float xi2 = __fmul_rn(-2.0f, fi.x), yi2 = __fmul_rn(-2.0f, fi.y);
    int lane_i = __builtin_amdgcn_readfirstlane(i & 63);
    int k_i    = __builtin_amdgcn_readfirstlane(i >> 6);

    float h[36];
    float mymin = FLT_MAX;
    #pragma unroll
    for (int k = 0; k < 36; ++k) {
        int j = lane + (k << 6);
        float hh = rank_h(f[j], xi2, yi2);
        if (k == k_i && lane == lane_i) hh = FLT_MAX;
        h[k] = hh;
        mymin = fminf(mymin, hh);
    }
    float g = mymin;
    g = fminf(g, __shfl_xor(g, 1, 64));
    g = fminf(g, __shfl_xor(g, 2, 64));
    g = fminf(g, __shfl_xor(g, 4, 64));
    float T = g;
    T = fmaxf(T, __shfl_xor(T, 8, 64));
    T = fmaxf(T, __shfl_xor(T, 16, 64));
    T = fmaxf(T, __shfl_xor(T, 32, 64));
    unsigned long long* mybuf = kbuf[wave];
    const unsigned long long lmask = (1ull << lane) - 1ull;
    int total = 0;
    #pragma unroll
    for (int k = 0; k < 36; ++k) {
        bool pred = h[k] <= T;
        unsigned long long mask = __ballot(pred);
        if (pred) {
            int pos = total + (int)__popcll(mask & lmask);
            if (pos < KCAP) {
                unsigned int bits = __float_as_uint(h[k]);
                if (bits == 0x80000000u) bits = 0u;
                unsigned int s = bits ^ (unsigned int)(((int)bits >> 31) | 0x80000000);
                mybuf[pos] = ((unsigned long long)s << 32) | (unsigned int)(lane + (k << 6));
            }
        }
        total += (int)__popcll(mask);
    }
    // no block barrier: kbuf[wave] is wave-private; same-wave DS ops in-order

    if (total >= KNN && total <= KCAP) {
        int padded = (total + 7) & ~7;                 // <= KCAP (64) always
        if (lane < padded - total) mybuf[total + lane] = ~0ull;
        for (int p = lane; p < total; p += 64) {
            unsigned long long mykey = mybuf[p];
            int rank = 0;
            for (int q = 0; q < padded; q += 8) {
                const ulonglong2* bp = (const ulonglong2*)&mybuf[q];
                ulonglong2 a = bp[0], b2 = bp[1], c2 = bp[2], d2 = bp[3];
                rank += (int)(a.x  < mykey) + (int)(a.y  < mykey)
                      + (int)(b2.x < mykey) + (int)(b2.y < mykey)
                      + (int)(c2.x < mykey) + (int)(c2.y < mykey)
                      + (int)(d2.x < mykey) + (int)(d2.y < mykey);
            }
            if (rank < KNN) {
                int j = (int)(unsigned int)(mykey & 0xFFFFFFFFull);
                idx[(b * MNODE + i) * KNN + rank] = j;
                atomicAdd(&cnt[b * MNODE + j], 1);
            }
        }
    } else {
        const unsigned long long SENT = ~0ull;
        unsigned long long k0 = SENT, k1 = SENT, k2 = SENT, k3 = SENT,
                           k4 = SENT, k5 = SENT, k6 = SENT, k7 = SENT;
        #pragma unroll
        for (int k = 0; k < 36; ++k) {
            unsigned int bits = __float_as_uint(h[k]);
            if (bits == 0x80000000u) bits = 0u;
            unsigned int s = bits ^ (unsigned int)(((int)bits >> 31) | 0x80000000);
            unsigned long long key = ((unsigned long long)s << 32) | (unsigned int)(lane + (k << 6));
            if (key < k7) {
                k7 = key;
                if (k7 < k6) { unsigned long long t = k6; k6 = k7; k7 = t; }
                if (k6 < k5) { unsigned long long t = k5; k5 = k6; k6 = t; }
                if (k5 < k4) { unsigned long long t = k4; k4 = k5; k5 = t; }
                if (k4 < k3) { unsigned long long t = k3; k3 = k4; k4 = t; }
                if (k3 < k2) { unsigned long long t = k2; k2 = k3; k3 = t; }
                if (k2 < k1) { unsigned long long t = k1; k1 = k2; k2 = t; }
                if (k1 < k0) { unsigned long long t = k0; k0 = k1; k1 = t; }
            }
        }
        unsigned long long mywin = 0;
        #pragma unroll
        for (int r = 0; r < KNN; ++r) {
            unsigned long long hh = k0;
            #pragma unroll
            for (int off = 32; off > 0; off >>= 1) {
                unsigned long long o = __shfl_xor(hh, off, 64);
                if (o < hh) hh = o;
            }
            if (lane == r) mywin = hh;
            if (k0 == hh) {
                k0 = k1; k1 = k2; k2 = k3; k3 = k4; k4 = k5; k5 = k6; k6 = k7; k7 = SENT;
            }
        }
        if (lane < KNN) {
            int j = (int)(unsigned int)(mywin & 0xFFFFFFFFull);
            idx[(b * MNODE + i) * KNN + lane] = j;
            atomicAdd(&cnt[b * MNODE + j], 1);
        }
    }
}

// Single-pass order-free scan + dinv + PS + fptr seed.
// offs only needs to give each node a DISJOINT range in rev[]; range order is
// irrelevant (gathers read [offs, offs+cnt) wherever it lands). So each block
// takes its base from an atomic ticket: base = atomicAdd(gtotal, block_sum).
// No cross-block ordering or residency assumption.
__global__ void __launch_bounds__(256) scan_kernel(
    const int* __restrict__ cnt, const float* __restrict__ S,
    float* __restrict__ dinv, float* __restrict__ PS,
    int* __restrict__ gtotal, int2* __restrict__ oc, int* __restrict__ fptr) {
    __shared__ int wsum[4];
    __shared__ int sbase;
    int tid = threadIdx.x;
    int lane = tid & 63, wv = tid >> 6;
    int gid = blockIdx.x * 256 + tid;
    int v = cnt[gid];
    float deg = (float)(KNN + v);
    float dv = 1.0f / sqrtf(deg + 1e-8f);
    dinv[gid] = dv;
    PS[gid * 2 + 0] = dv * S[gid * 2 + 0];
    PS[gid * 2 + 1] = dv * S[gid * 2 + 1];
    int x = v;
    #pragma unroll
    for (int off = 1; off < 64; off <<= 1) {
        int y = __shfl_up(x, off, 64);
        if (lane >= off) x += y;
    }
    if (lane == 63) wsum[wv] = x;
    __syncthreads();
    if (tid == 0) sbase = atomicAdd(gtotal, wsum[0] + wsum[1] + wsum[2] + wsum[3]);
    __syncthreads();
    int base = sbase;
    for (int w = 0; w < wv; ++w) base += wsum[w];
    int o = base + x - v;
    oc[gid] = make_int2(o, v);
    fptr[gid] = o;
}

// scatter each directed edge i->j into j's reverse list; fptr pre-seeded
// with offs, so the atomic returns the absolute slot.
__global__ void fill_kernel(const int* __restrict__ idx,
                            int* __restrict__ fptr, int* __restrict__ rev) {
    int gid = blockIdx.x * blockDim.x + threadIdx.x;
    if (gid >= BM * KNN) return;
    int b = gid / (MNODE * KNN);
    int rem = gid - b * (MNODE * KNN);
    int i = rem / KNN;
    int gj = b * MNODE + idx[gid];
    int pos = atomicAdd(&fptr[gj], 1);
    rev[pos] = b * MNODE + i;
}

// zA[i][c] = 0.5*dinv[i] * sum over neighbors j (both directions) with j%9==c of PS[j]
// 9 threads per row (one per c). Also emits zAw[i][c] = dinv[i]*zA[i][c]
// so gather2 needs no dinv[gj] load per neighbor.
__global__ void __launch_bounds__(256) gather1_kernel(
    const int* __restrict__ idx, const int2* __restrict__ oc,
    const int* __restrict__ rev, const float* __restrict__ dinv, const float* __restrict__ PS,
    float* __restrict__ zA, float* __restrict__ zAw) {
    int gid = blockIdx.x * blockDim.x + threadIdx.x;
    if (gid >= BM * CFREQ) return;
    int gi = gid / CFREQ;
    int c = gid - gi * CFREQ;
    int b = gi / MNODE;
    float ax = 0.0f, ay = 0.0f;
    #pragma unroll
    for (int k = 0; k < KNN; ++k) {
        int gj = b * MNODE + idx[gi * KNN + k];
        bool m = (gj % CFREQ) == c;
        float2 p = ((const float2*)PS)[gj];
        ax += m ? p.x : 0.0f;
        ay += m ? p.y : 0.0f;
    }
    int2 ocv = oc[gi];
    int o = ocv.x, e = o + ocv.y;
    for (int p_ = o; p_ < e; ++p_) {
        int gk = rev[p_];
        bool m = (gk % CFREQ) == c;
        float2 p = ((const float2*)PS)[gk];
        ax += m ? p.x : 0.0f;
        ay += m ? p.y : 0.0f;
    }
    float dv = dinv[gi];
    float s = dv * 0.5f;
    float zx = s * ax, zy = s * ay;
    zA[gid * 2 + 0] = zx;
    zA[gid * 2 + 1] = zy;
    zAw[gid * 2 + 0] = dv * zx;
    zAw[gid * 2 + 1] = dv * zy;
}

// zF[i][c] = cb*zA[i][c] + cc*zB[i][c], with
// zB[i][c] = 0.5*dinv[i] * sum over neighbors of zAw[j][c]  (zAw pre-folds dinv[j]).
// Folding the Chebyshev combine here saves rowproj half its z loads.
__global__ void __launch_bounds__(256) gather2_kernel(
    const int* __restrict__ idx, const int2* __restrict__ oc,
    const int* __restrict__ rev, const float* __restrict__ dinv,
    const float* __restrict__ zA, const float* __restrict__ zAw,
    const float* __restrict__ theta, const float* __restrict__ approx,
    float* __restrict__ zF) {
    int gid = blockIdx.x * blockDim.x + threadIdx.x;
    if (gid >= BM * CFREQ) return;
    float a1 = theta[0] * approx[1] + theta[1] * approx[4];
    float a2 = theta[0] * approx[2] + theta[1] * approx[5];
    float cb = -a1, cc = 2.0f * a2;
    int gi = gid / CFREQ;
    int c = gid - gi * CFREQ;
    int b = gi / MNODE;
    float ax = 0.0f, ay = 0.0f;
    #pragma unroll
    for (int k = 0; k < KNN; ++k) {
        int gj = b * MNODE + idx[gi * KNN + k];
        float2 v = ((const float2*)zAw)[gj * CFREQ + c];
        ax += v.x;
        ay += v.y;
    }
    int2 ocv = oc[gi];
    int o = ocv.x, e = o + ocv.y;
    for (int p = o; p < e; ++p) {
        int gk = rev[p];
        float2 v = ((const float2*)zAw)[gk * CFREQ + c];
        ax += v.x;
        ay += v.y;
    }
    float s = dinv[gi] * 0.5f;
    float2 za = ((const float2*)zA)[gid];
    zF[gid * 2 + 0] = cb * za.x + cc * (s * ax);
    zF[gid * 2 + 1] = cb * za.y + cc * (s * ay);
}

// per row r: z (9 complex, pre-combined zF + ca*S at c==cr) -> u = z . FE
// -> csilu -> eo projection (complex scalar)
__global__ void __launch_bounds__(256) rowproj_kernel(
    const float* __restrict__ S, const float* __restrict__ zF,
    const float* __restrict__ FE, const float* __restrict__ eoWr, const float* __restrict__ eoWi,
    const float* __restrict__ theta, const float* __restrict__ approx,
    float* __restrict__ Sout) {
    int wave = threadIdx.x >> 6;
    int lane = threadIdx.x & 63;
    int r = blockIdx.x * 4 + wave;
    if (r >= BM) return;
    float a0 = theta[0] * approx[0] + theta[1] * approx[3];
    float a2 = theta[0] * approx[2] + theta[1] * approx[5];
    float ca = a0 - a2;
    int cr = r % CFREQ;
    float sr = S[r * 2 + 0], si = S[r * 2 + 1];
    int e1 = lane + 64;
    float ur0 = 0.0f, ui0 = 0.0f, ur1 = 0.0f, ui1 = 0.0f;
    #pragma unroll
    for (int c = 0; c < CFREQ; ++c) {
        float2 zf = ((const float2*)zF)[r * CFREQ + c];
        float zr = zf.x, zi = zf.y;
        if (c == cr) { zr += ca * sr; zi += ca * si; }
        float fr0 = FE[(c * EMBED + lane) * 2 + 0], fi0 = FE[(c * EMBED + lane) * 2 + 1];
        float fr1 = FE[(c * EMBED + e1) * 2 + 0],  fi1 = FE[(c * EMBED + e1) * 2 + 1];
        ur0 += zr * fr0 - zi * fi0;  ui0 += zr * fi0 + zi * fr0;
        ur1 += zr * fr1 - zi * fi1;  ui1 += zr * fi1 + zi * fr1;
    }
    float hr0 = silu_f(ur0), hi0 = silu_f(ui0);
    float hr1 = silu_f(ur1), hi1 = silu_f(ui1);
    float wr0 = eoWr[lane], wi0 = eoWi[lane], wr1 = eoWr[e1], wi1 = eoWi[e1];
    float p = hr0 * wr0 - hi0 * wi0 + hr1 * wr1 - hi1 * wi1;
    float q = hr0 * wi0 + hi0 * wr0 + hr1 * wi1 + hi1 * wr1;
    #pragma unroll
    for (int off = 32; off > 0; off >>= 1) {
        p += __shfl_down(p, off, 64);
        q += __shfl_down(q, off, 64);
    }
    if (lane == 0) {
        Sout[r * 2 + 0] = p;
        Sout[r * 2 + 1] = q;
    }
}

// per (b,n): irfft96 -> inorm+silu -> W1 -> inorm+silu -> W2 -> + trend_emb -> W3 -> out
// HROWS=16 rows per 1024-thread block (LDS 53.6KB < 64KB workgroup limit;
// 2 blocks/CU x 16 waves = 32 waves/CU). Trend recomputed inline from x
// (bit-exact expression), staged through hraw (overwritten by irfft).
__global__ void __launch_bounds__(1024) head_kernel(
    const float* __restrict__ Sout, const float* __restrict__ x,
    const float* __restrict__ n1w, const float* __restrict__ n1b,
    const float* __restrict__ n2w, const float* __restrict__ n2b,
    const float* __restrict__ W1w, const float* __restrict__ W1b,
    const float* __restrict__ W2w, const float* __restrict__ W2b,
    const float* __restrict__ Wtw, const float* __restrict__ Wtb,
    const float* __restrict__ W3w, const float* __restrict__ W3b,
    float* __restrict__ out) {
    __shared__ float tabc[96], tabs[96];
    __shared__ float srow[HROWS][18];
    __shared__ float tbuf[HROWS][96];
    __shared__ float hraw[HROWS][96];
    __shared__ float sH[HROWS][96];
    __shared__ float h2[HROWS][64];
    __shared__ float s3[HROWS][64];
    __shared__ float red[HROWS][2];
    __shared__ float wbuf[6240];
    int tid = threadIdx.x;
    int wave = tid >> 6, lane = tid & 63;
    int bn0 = blockIdx.x * HROWS;
    if (tid < 96) {
        double a = 6.283185307179586476925286766559 * (double)tid / 96.0;
        tabc[tid] = (float)cos(a);
        tabs[tid] = (float)sin(a);
    }
    // stage x column into hraw (temp), srow
    for (int i = tid; i < HROWS * 96; i += 1024) {
        int g = i / 96, t = i - g * 96;
        int bn = bn0 + g;
        hraw[g][t] = x[(bn >> 8) * TN + t * NNODE + (bn & 255)];
    }
    if (tid < HROWS * 18) {
        int g = tid / 18, k = tid - g * 18;
        srow[g][k] = Sout[(bn0 + g) * 18 + k];
    }
    __syncthreads();
    // trend (bit-exact expression) from staged x
    for (int i = tid; i < HROWS * 96; i += 1024) {
        int g = i / 96, t = i - g * 96;
        int tm = t > 0 ? t - 1 : 0;
        int tp = t < SEQ - 1 ? t + 1 : SEQ - 1;
        tbuf[g][t] = (hraw[g][tm] + hraw[g][t] + hraw[g][tp]) * (1.0f / 3.0f);
    }
    __syncthreads();
    // irfft96 for all rows (overwrites hraw; reads only srow/tab)
    for (int i = tid; i < HROWS * 96; i += 1024) {
        int g = i / 96, t = i - g * 96;
        float acc = srow[g][0];   // Im(bin0) ignored by irfft
        #pragma unroll
        for (int c = 1; c < CFREQ; ++c) {
            int k = (c * t) % 96;
            acc += 2.0f * (srow[g][2 * c] * tabc[k] - srow[g][2 * c + 1] * tabs[k]);
        }
        hraw[g][t] = acc * 0.10206207261596575f;  // 1/sqrt(96)
    }
    __syncthreads();
    // mean of row `wave`
    {
        float v = hraw[wave][lane] + ((lane < 32) ? hraw[wave][64 + lane] : 0.0f);
        #pragma unroll
        for (int off = 32; off > 0; off >>= 1) v += __shfl_down(v, off, 64);
        if (lane == 0) red[wave][0] = v * (1.0f / 96.0f);
    }
    __syncthreads();
    // var of row `wave`
    {
        float mu = red[wave][0];
        float d0 = hraw[wave][lane] - mu;
        float v = d0 * d0;
        if (lane < 32) { float d1 = hraw[wave][64 + lane] - mu; v += d1 * d1; }
        #pragma unroll
        for (int off = 32; off > 0; off >>= 1) v += __shfl_down(v, off, 64);
        if (lane == 0) red[wave][1] = v * (1.0f / 96.0f);
    }
    __syncthreads();
    // inorm1 + silu -> sH; stage W1 (97-pad)
    for (int i = tid; i < HROWS * 96; i += 1024) {
        int g = i / 96, t = i - g * 96;
        int n = (bn0 + g) & 255;
        float xn = (hraw[g][t] - red[g][0]) / sqrtf(red[g][1] + 1e-5f) * n1w[n] + n1b[n];
        sH[g][t] = silu_f(xn);
    }
    for (int i = tid; i < HIDDEN * 96; i += 1024) {
        int rr = i / 96;
        wbuf[rr * 97 + (i - rr * 96)] = W1w[i];
    }
    __syncthreads();
    // W1 matvec: wave g, lane r
    float v1;
    {
        float acc = W1b[lane];
        #pragma unroll 8
        for (int t = 0; t < 96; ++t) acc += sH[wave][t] * wbuf[lane * 97 + t];
        v1 = acc;
    }
    // inorm2 + silu (pure in-wave) -> h2
    {
        float s = v1;
        #pragma unroll
        for (int off = 32; off > 0; off >>= 1) s += __shfl_down(s, off, 64);
        s = __shfl(s, 0, 64);
        float mu2 = s * (1.0f / 64.0f);
        float d = v1 - mu2;
        float vs = d * d;
        #pragma unroll
        for (int off = 32; off > 0; off >>= 1) vs += __shfl_down(vs, off, 64);
        vs = __shfl(vs, 0, 64);
        float var2 = vs * (1.0f / 64.0f);
        int n = (bn0 + wave) & 255;
        float xn = (v1 - mu2) / sqrtf(var2 + 1e-5f) * n2w[n] + n2b[n];
        h2[wave][lane] = silu_f(xn);
    }
    __syncthreads();   // wbuf(W1) reads + h2 writes done
    for (int i = tid; i < HIDDEN * HIDDEN; i += 1024) {
        wbuf[(i >> 6) * 65 + (i & 63)] = W2w[i];
    }
    __syncthreads();
    float v3;
    {
        float acc = W2b[lane];
        #pragma unroll 8
        for (int h = 0; h < 64; ++h) acc += h2[wave][h] * wbuf[lane * 65 + h];
        v3 = acc;
    }
    __syncthreads();   // wbuf(W2) reads done
    for (int i = tid; i < HIDDEN * 96; i += 1024) {
        int rr = i / 96;
        wbuf[rr * 97 + (i - rr * 96)] = Wtw[i];
    }
    __syncthreads();
    {
        float acc = Wtb[lane];
        #pragma unroll 8
        for (int t = 0; t < 96; ++t) acc += tbuf[wave][t] * wbuf[lane * 97 + t];
        s3[wave][lane] = v3 + acc;
    }
    __syncthreads();   // wbuf(Wt) reads + s3 writes done
    for (int i = tid; i < 96 * HIDDEN; i += 1024) {
        wbuf[(i >> 6) * 65 + (i & 63)] = W3w[i];
    }
    __syncthreads();
    for (int i = tid; i < HROWS * 96; i += 1024) {
        int g = i / 96, t = i - g * 96;
        float acc = W3b[t];
        #pragma unroll 8
        for (int h = 0; h < 64; ++h) acc += s3[g][h] * wbuf[t * 65 + h];
        out[(bn0 + g) * 96 + t] = acc;
    }
}

extern "C" void kernel_launch(void* const* d_in, const int* in_sizes, int n_in,
                              void* d_out, int out_size, void* d_ws, size_t ws_size,
                              hipStream_t stream) {
    const float* x     = (const float*)d_in[0];
    const float* approx= (const float*)d_in[1];
    const float* theta = (const float*)d_in[2];
    const float* frWr  = (const float*)d_in[3];
    const float* frWi  = (const float*)d_in[4];
    const float* eoWr  = (const float*)d_in[5];
    const float* eoWi  = (const float*)d_in[6];
    const float* femb  = (const float*)d_in[7];
    const float* n1w   = (const float*)d_in[8];
    const float* n1b   = (const float*)d_in[9];
    const float* n2w   = (const float*)d_in[10];
    const float* n2b   = (const float*)d_in[11];
    const float* W1w   = (const float*)d_in[12];
    const float* W1b   = (const float*)d_in[13];
    const float* W2w   = (const float*)d_in[14];
    const float* W2b   = (const float*)d_in[15];
    const float* Wtw   = (const float*)d_in[16];
    const float* Wtb   = (const float*)d_in[17];
    const float* W3w   = (const float*)d_in[18];
    const float* W3b   = (const float*)d_in[19];
    float* out = (float*)d_out;

    char* ws = (char*)d_ws;
    size_t off = 0;
    auto alloc = [&](size_t bytes) -> void* {
        void* p = ws + off;
        off = (off + bytes + 255) & ~(size_t)255;
        return p;
    };
    float* S     = (float*)alloc((size_t)BM * 2 * 4);
    int*   idx   = (int*)  alloc((size_t)BM * KNN * 4);
    float* dinv  = (float*)alloc((size_t)BM * 4);
    float* PS    = (float*)alloc((size_t)BM * 2 * 4);
    float* FE    = (float*)alloc((size_t)FEW * 2 * 4);
    float* Sout  = (float*)alloc((size_t)BM * 2 * 4);
    int2*  oc    = (int2*) alloc((size_t)BM * 8);
    int*   rev   = (int*)  alloc((size_t)BM * KNN * 4);
    float* zA    = (float*)alloc((size_t)BM * CFREQ * 2 * 4);
    float* zAw   = (float*)alloc((size_t)BM * CFREQ * 2 * 4);
    float* zF    = (float*)alloc((size_t)BM * CFREQ * 2 * 4);
    int*   cnt   = (int*)  alloc((size_t)BM * 4);
    int*   fptr  = (int*)  alloc((size_t)BM * 4);
    int*   gtotal= (int*)  alloc(256);

    // no memset: cnt+gtotal zeroed by prep; fptr seeded by scan_kernel
    prep_kernel<<<(BM + FEW + 255) / 256, 256, 0, stream>>>(x, S, cnt, femb, frWr, frWi, FE, gtotal);
    knn_kernel<<<dim3(MNODE / 4, BATCH), 256, 0, stream>>>(S, idx, cnt);
    scan_kernel<<<NBLK, 256, 0, stream>>>(cnt, S, dinv, PS, gtotal, oc, fptr);
    fill_kernel<<<(BM * KNN + 255) / 256, 256, 0, stream>>>(idx, fptr, rev);
    gather1_kernel<<<(BM * CFREQ + 255) / 256, 256, 0, stream>>>(idx, oc, rev, dinv, PS, zA, zAw);
    gather2_kernel<<<(BM * CFREQ + 255) / 256, 256, 0, stream>>>(idx, oc, rev, dinv, zA, zAw,
                                                                 theta, approx, zF);
    rowproj_kernel<<<BM / 4, 256, 0, stream>>>(S, zF, FE, eoWr, eoWi, theta, approx, Sout);
    head_kernel<<<BATCH * NNODE / HROWS, 1024, 0, stream>>>(Sout, x, n1w, n1b, n2w, n2b,
                                                            W1w, W1b, W2w, W2b, Wtw, Wtb, W3w, W3b, out);
}

// Round 13
// 239.002 us; speedup vs baseline: 1.0177x; 1.0177x over previous
//
#include <hip/hip_runtime.h>
#include <math.h>
#include <float.h>

#define BATCH 16
#define SEQ 96
#define NNODE 256
#define CFREQ 9
#define MNODE (NNODE * CFREQ)      // 2304
#define BM (BATCH * MNODE)         // 36864
#define KNN 8
#define EMBED 128
#define HIDDEN 64
#define TN (SEQ * NNODE)           // 24576
#define KCAP 64
#define NBLK (BM / 256)            // 144 scan blocks
#define HROWS 16                   // head rows per block (1024 threads)
#define FEW (CFREQ * EMBED)        // 1152 fe outputs

__constant__ float COS16[16] = {
    1.0f, 0.9238795325112867f, 0.7071067811865476f, 0.3826834323650898f,
    0.0f, -0.3826834323650898f, -0.7071067811865476f, -0.9238795325112867f,
    -1.0f, -0.9238795325112867f, -0.7071067811865476f, -0.3826834323650898f,
    0.0f, 0.3826834323650898f, 0.7071067811865476f, 0.9238795325112867f};
__constant__ float SIN16[16] = {
    0.0f, 0.3826834323650898f, 0.7071067811865476f, 0.9238795325112867f,
    1.0f, 0.9238795325112867f, 0.7071067811865476f, 0.3826834323650898f,
    0.0f, -0.3826834323650898f, -0.7071067811865476f, -0.9238795325112867f,
    -1.0f, -0.9238795325112867f, -0.7071067811865476f, -0.3826834323650898f};

static __device__ __forceinline__ float silu_f(float x) {
    return x / (1.0f + expf(-x));
}

// ranking value h = |fj|^2 - 2*(fi . fj) (monotone with d = sqi + h)
static __device__ __forceinline__ float rank_h(float2 fj, float xi2, float yi2) {
    float sqj = __fmaf_rn(fj.y, fj.y, __fmul_rn(fj.x, fj.x));
    return __fmaf_rn(xi2, fj.x, __fmaf_rn(yi2, fj.y, sqj));
}

// Fused: per-(b,n,c) thread computes trend inline (bit-exact expression) and
// the rfft16 bin; zeroes cnt and the scan ticket. Extra blocks compute FE.
__global__ void __launch_bounds__(256) prep_kernel(
    const float* __restrict__ x, float* __restrict__ S, int* __restrict__ cnt,
    const float* __restrict__ femb, const float* __restrict__ Wr,
    const float* __restrict__ Wi, float* __restrict__ FE, int* __restrict__ gtotal) {
    int gid = blockIdx.x * 256 + threadIdx.x;
    if (gid < BM) {
        if (gid == 0) *gtotal = 0;
        cnt[gid] = 0;
        int b = gid / MNODE;
        int m = gid - b * MNODE;
        int n = m / CFREQ;
        int c = m - n * CFREQ;
        const float* xb = x + b * TN + n;
        float xv[17];
        #pragma unroll
        for (int t = 0; t < 17; ++t) xv[t] = xb[t * NNODE];
        float re = 0.0f, im = 0.0f;
        #pragma unroll
        for (int t = 0; t < 16; ++t) {
            int tm = t > 0 ? t - 1 : 0;
            float tr = (xv[tm] + xv[t] + xv[t + 1]) * (1.0f / 3.0f);
            float s = xv[t] - tr;
            int k = (c * t) & 15;
            re += s * COS16[k];
            im -= s * SIN16[k];
        }
        S[gid * 2 + 0] = re * 0.25f;
        S[gid * 2 + 1] = im * 0.25f;
    } else {
        int f = gid - BM;
        if (f < FEW) {
            int c = f / EMBED;
            int e = f - c * EMBED;
            float ar = 0.0f, ai = 0.0f;
            for (int k = 0; k < EMBED; ++k) {
                float fv = femb[c * EMBED + k];
                ar += fv * Wr[e * EMBED + k];
                ai += fv * Wi[e * EMBED + k];
            }
            FE[f * 2 + 0] = ar;
            FE[f * 2 + 1] = ai;
        }
    }
}

// One WAVE per row, 4 rows per 256-block. Exact top-8.
//  P1: h[36] cached in regs; per-lane min.
//  T : max over 8 disjoint 8-lane groups of group-min of lane minima.
//  P2: ballot/popcll-prefix append of survivor u64 keys into wave-private
//      LDS buffer.
//  P3 (guarded: KNN <= total <= KCAP): pad to multiple of 8 with SENT,
//      8-wide rank selection via 4x ds_read_b128.
//  Else: exact fallback from the h cache (insert network + 8-round merge).
__global__ void __launch_bounds__(256, 8) knn_kernel(const float* __restrict__ S,
                                                     int* __restrict__ idx, int* __restrict__ cnt) {
    __shared__ float2 f[MNODE];                        // 18432 B
    __shared__ unsigned long long kbuf[4][KCAP];       // 2048 B -> total 20480 = 160K/8
    int b = blockIdx.y;
    int tid = threadIdx.x;
    for (int t = tid; t < MNODE; t += 256) {
        f[t] = make_float2(S[(b * MNODE + t) * 2 + 0], S[(b * MNODE + t) * 2 + 1]);
    }
    __syncthreads();
    int wave = tid >> 6, lane = tid & 63;
    int i = blockIdx.x * 4 + wave;
    float2 fi = f[i];
    float xi2 = __fmul_rn(-2.0f, fi.x), yi2 = __fmul_rn(-2.0f, fi.y);
    int lane_i = __builtin_amdgcn_readfirstlane(i & 63);
    int k_i    = __builtin_amdgcn_readfirstlane(i >> 6);

    float h[36];
    float mymin = FLT_MAX;
    #pragma unroll
    for (int k = 0; k < 36; ++k) {
        int j = lane + (k << 6);
        float hh = rank_h(f[j], xi2, yi2);
        if (k == k_i && lane == lane_i) hh = FLT_MAX;
        h[k] = hh;
        mymin = fminf(mymin, hh);
    }
    float g = mymin;
    g = fminf(g, __shfl_xor(g, 1, 64));
    g = fminf(g, __shfl_xor(g, 2, 64));
    g = fminf(g, __shfl_xor(g, 4, 64));
    float T = g;
    T = fmaxf(T, __shfl_xor(T, 8, 64));
    T = fmaxf(T, __shfl_xor(T, 16, 64));
    T = fmaxf(T, __shfl_xor(T, 32, 64));
    unsigned long long* mybuf = kbuf[wave];
    const unsigned long long lmask = (1ull << lane) - 1ull;
    int total = 0;
    #pragma unroll
    for (int k = 0; k < 36; ++k) {
        bool pred = h[k] <= T;
        unsigned long long mask = __ballot(pred);
        if (pred) {
            int pos = total + (int)__popcll(mask & lmask);
            if (pos < KCAP) {
                unsigned int bits = __float_as_uint(h[k]);
                if (bits == 0x80000000u) bits = 0u;
                unsigned int s = bits ^ (unsigned int)(((int)bits >> 31) | 0x80000000);
                mybuf[pos] = ((unsigned long long)s << 32) | (unsigned int)(lane + (k << 6));
            }
        }
        total += (int)__popcll(mask);
    }
    // no block barrier: kbuf[wave] is wave-private; same-wave DS ops in-order

    if (total >= KNN && total <= KCAP) {
        int padded = (total + 7) & ~7;                 // <= KCAP (64) always
        if (lane < padded - total) mybuf[total + lane] = ~0ull;
        for (int p = lane; p < total; p += 64) {
            unsigned long long mykey = mybuf[p];
            int rank = 0;
            for (int q = 0; q < padded; q += 8) {
                const ulonglong2* bp = (const ulonglong2*)&mybuf[q];
                ulonglong2 a = bp[0], b2 = bp[1], c2 = bp[2], d2 = bp[3];
                rank += (int)(a.x  < mykey) + (int)(a.y  < mykey)
                      + (int)(b2.x < mykey) + (int)(b2.y < mykey)
                      + (int)(c2.x < mykey) + (int)(c2.y < mykey)
                      + (int)(d2.x < mykey) + (int)(d2.y < mykey);
            }
            if (rank < KNN) {
                int j = (int)(unsigned int)(mykey & 0xFFFFFFFFull);
                idx[(b * MNODE + i) * KNN + rank] = j;
                atomicAdd(&cnt[b * MNODE + j], 1);
            }
        }
    } else {
        const unsigned long long SENT = ~0ull;
        unsigned long long k0 = SENT, k1 = SENT, k2 = SENT, k3 = SENT,
                           k4 = SENT, k5 = SENT, k6 = SENT, k7 = SENT;
        #pragma unroll
        for (int k = 0; k < 36; ++k) {
            unsigned int bits = __float_as_uint(h[k]);
            if (bits == 0x80000000u) bits = 0u;
            unsigned int s = bits ^ (unsigned int)(((int)bits >> 31) | 0x80000000);
            unsigned long long key = ((unsigned long long)s << 32) | (unsigned int)(lane + (k << 6));
            if (key < k7) {
                k7 = key;
                if (k7 < k6) { unsigned long long t = k6; k6 = k7; k7 = t; }
                if (k6 < k5) { unsigned long long t = k5; k5 = k6; k6 = t; }
                if (k5 < k4) { unsigned long long t = k4; k4 = k5; k5 = t; }
                if (k4 < k3) { unsigned long long t = k3; k3 = k4; k4 = t; }
                if (k3 < k2) { unsigned long long t = k2; k2 = k3; k3 = t; }
                if (k2 < k1) { unsigned long long t = k1; k1 = k2; k2 = t; }
                if (k1 < k0) { unsigned long long t = k0; k0 = k1; k1 = t; }
            }
        }
        unsigned long long mywin = 0;
        #pragma unroll
        for (int r = 0; r < KNN; ++r) {
            unsigned long long hh = k0;
            #pragma unroll
            for (int off = 32; off > 0; off >>= 1) {
                unsigned long long o = __shfl_xor(hh, off, 64);
                if (o < hh) hh = o;
            }
            if (lane == r) mywin = hh;
            if (k0 == hh) {
                k0 = k1; k1 = k2; k2 = k3; k3 = k4; k4 = k5; k5 = k6; k6 = k7; k7 = SENT;
            }
        }
        if (lane < KNN) {
            int j = (int)(unsigned int)(mywin & 0xFFFFFFFFull);
            idx[(b * MNODE + i) * KNN + lane] = j;
            atomicAdd(&cnt[b * MNODE + j], 1);
        }
    }
}

// Single-pass order-free scan + dinv + PS + fptr seed.
// offs only needs disjoint ranges; block base from an atomic ticket.
__global__ void __launch_bounds__(256) scan_kernel(
    const int* __restrict__ cnt, const float* __restrict__ S,
    float* __restrict__ dinv, float* __restrict__ PS,
    int* __restrict__ gtotal, int2* __restrict__ oc, int* __restrict__ fptr) {
    __shared__ int wsum[4];
    __shared__ int sbase;
    int tid = threadIdx.x;
    int lane = tid & 63, wv = tid >> 6;
    int gid = blockIdx.x * 256 + tid;
    int v = cnt[gid];
    float deg = (float)(KNN + v);
    float dv = 1.0f / sqrtf(deg + 1e-8f);
    dinv[gid] = dv;
    PS[gid * 2 + 0] = dv * S[gid * 2 + 0];
    PS[gid * 2 + 1] = dv * S[gid * 2 + 1];
    int x = v;
    #pragma unroll
    for (int off = 1; off < 64; off <<= 1) {
        int y = __shfl_up(x, off, 64);
        if (lane >= off) x += y;
    }
    if (lane == 63) wsum[wv] = x;
    __syncthreads();
    if (tid == 0) sbase = atomicAdd(gtotal, wsum[0] + wsum[1] + wsum[2] + wsum[3]);
    __syncthreads();
    int base = sbase;
    for (int w = 0; w < wv; ++w) base += wsum[w];
    int o = base + x - v;
    oc[gid] = make_int2(o, v);
    fptr[gid] = o;
}

// scatter each directed edge i->j into j's reverse list; fptr pre-seeded
// with offs, so the atomic returns the absolute slot.
__global__ void fill_kernel(const int* __restrict__ idx,
                            int* __restrict__ fptr, int* __restrict__ rev) {
    int gid = blockIdx.x * blockDim.x + threadIdx.x;
    if (gid >= BM * KNN) return;
    int b = gid / (MNODE * KNN);
    int rem = gid - b * (MNODE * KNN);
    int i = rem / KNN;
    int gj = b * MNODE + idx[gid];
    int pos = atomicAdd(&fptr[gj], 1);
    rev[pos] = b * MNODE + i;
}

// zA[i][c] = 0.5*dinv[i] * sum over neighbors j (both directions) with j%9==c of PS[j]
// 9 threads per row (one per c). Also emits zAw[i][c] = dinv[i]*zA[i][c].
__global__ void __launch_bounds__(256) gather1_kernel(
    const int* __restrict__ idx, const int2* __restrict__ oc,
    const int* __restrict__ rev, const float* __restrict__ dinv, const float* __restrict__ PS,
    float* __restrict__ zA, float* __restrict__ zAw) {
    int gid = blockIdx.x * blockDim.x + threadIdx.x;
    if (gid >= BM * CFREQ) return;
    int gi = gid / CFREQ;
    int c = gid - gi * CFREQ;
    int b = gi / MNODE;
    float ax = 0.0f, ay = 0.0f;
    #pragma unroll
    for (int k = 0; k < KNN; ++k) {
        int gj = b * MNODE + idx[gi * KNN + k];
        bool m = (gj % CFREQ) == c;
        float2 p = ((const float2*)PS)[gj];
        ax += m ? p.x : 0.0f;
        ay += m ? p.y : 0.0f;
    }
    int2 ocv = oc[gi];
    int o = ocv.x, e = o + ocv.y;
    for (int p_ = o; p_ < e; ++p_) {
        int gk = rev[p_];
        bool m = (gk % CFREQ) == c;
        float2 p = ((const float2*)PS)[gk];
        ax += m ? p.x : 0.0f;
        ay += m ? p.y : 0.0f;
    }
    float dv = dinv[gi];
    float s = dv * 0.5f;
    float zx = s * ax, zy = s * ay;
    zA[gid * 2 + 0] = zx;
    zA[gid * 2 + 1] = zy;
    zAw[gid * 2 + 0] = dv * zx;
    zAw[gid * 2 + 1] = dv * zy;
}

// Fused gather2 + rowproj: one WAVE per row.
//  Phase 1 (lanes 0..35): quad q=lane>>2 owns c=q; sub=lane&3 strides the
//    KNN + rev neighbor list 4-ways over zAw; quad-reduce via shfl_xor(1,2)
//    (quads are lane-aligned); sub==0 combines with zA (Chebyshev fold) and
//    writes zf[c] to the wave's LDS slot. No barrier: same-wave DS ops are
//    in-order (knn-proven invariant), writes precede reads in program order.
//  Phase 2 (all 64 lanes): rowproj from LDS zf (u = z.FE -> csilu -> eo).
// Eliminates the zF global round-trip and one launch.
__global__ void __launch_bounds__(256) g2proj_kernel(
    const int* __restrict__ idx, const int2* __restrict__ oc,
    const int* __restrict__ rev, const float* __restrict__ dinv,
    const float* __restrict__ zA, const float* __restrict__ zAw,
    const float* __restrict__ S, const float* __restrict__ FE,
    const float* __restrict__ eoWr, const float* __restrict__ eoWi,
    const float* __restrict__ theta, const float* __restrict__ approx,
    float* __restrict__ Sout) {
    __shared__ float2 zfb[4][CFREQ];   // 288 B
    int wave = threadIdx.x >> 6;
    int lane = threadIdx.x & 63;
    int r = blockIdx.x * 4 + wave;
    if (r >= BM) return;
    float a0 = theta[0] * approx[0] + theta[1] * approx[3];
    float a1 = theta[0] * approx[1] + theta[1] * approx[4];
    float a2 = theta[0] * approx[2] + theta[1] * approx[5];
    float ca = a0 - a2, cb = -a1, cc = 2.0f * a2;
    int b = r / MNODE;
    int2 ocv = oc[r];
    if (lane < 36) {
        int c = lane >> 2, sub = lane & 3;
        float ax = 0.0f, ay = 0.0f;
        #pragma unroll
        for (int k = sub; k < KNN; k += 4) {
            int gj = b * MNODE + idx[r * KNN + k];
            float2 v = ((const float2*)zAw)[gj * CFREQ + c];
            ax += v.x;
            ay += v.y;
        }
        int o = ocv.x, e = o + ocv.y;
        for (int p = o + sub; p < e; p += 4) {
            int gk = rev[p];
            float2 v = ((const float2*)zAw)[gk * CFREQ + c];
            ax += v.x;
            ay += v.y;
        }
        ax += __shfl_xor(ax, 1, 64);  ay += __shfl_xor(ay, 1, 64);
        ax += __shfl_xor(ax, 2, 64);  ay += __shfl_xor(ay, 2, 64);
        if (sub == 0) {
            float s = dinv[r] * 0.5f;
            float2 za = ((const float2*)zA)[r * CFREQ + c];
            zfb[wave][c] = make_float2(cb * za.x + cc * (s * ax),
                                       cb * za.y + cc * (s * ay));
        }
    }
    // same-wave LDS ordering: ds_writes above issue before the ds_reads below
    int cr = r % CFREQ;
    float sr = S[r * 2 + 0], si = S[r * 2 + 1];
    int e1 = lane + 64;
    float ur0 = 0.0f, ui0 = 0.0f, ur1 = 0.0f, ui1 = 0.0f;
    #pragma unroll
    for (int c = 0; c < CFREQ; ++c) {
        float2 zf = zfb[wave][c];
        float zr = zf.x, zi = zf.y;
        if (c == cr) { zr += ca * sr; zi += ca * si; }
        float fr0 = FE[(c * EMBED + lane) * 2 + 0], fi0 = FE[(c * EMBED + lane) * 2 + 1];
        float fr1 = FE[(c * EMBED + e1) * 2 + 0],  fi1 = FE[(c * EMBED + e1) * 2 + 1];
        ur0 += zr * fr0 - zi * fi0;  ui0 += zr * fi0 + zi * fr0;
        ur1 += zr * fr1 - zi * fi1;  ui1 += zr * fi1 + zi * fr1;
    }
    float hr0 = silu_f(ur0), hi0 = silu_f(ui0);
    float hr1 = silu_f(ur1), hi1 = silu_f(ui1);
    float wr0 = eoWr[lane], wi0 = eoWi[lane], wr1 = eoWr[e1], wi1 = eoWi[e1];
    float p = hr0 * wr0 - hi0 * wi0 + hr1 * wr1 - hi1 * wi1;
    float q = hr0 * wi0 + hi0 * wr0 + hr1 * wi1 + hi1 * wr1;
    #pragma unroll
    for (int off = 32; off > 0; off >>= 1) {
        p += __shfl_down(p, off, 64);
        q += __shfl_down(q, off, 64);
    }
    if (lane == 0) {
        Sout[r * 2 + 0] = p;
        Sout[r * 2 + 1] = q;
    }
}

// per (b,n): irfft96 -> inorm+silu -> W1 -> inorm+silu -> W2 -> + trend_emb -> W3 -> out
// HROWS=16 rows per 1024-thread block. Trend recomputed inline from x
// (bit-exact expression), staged through hraw (overwritten by irfft).
__global__ void __launch_bounds__(1024) head_kernel(
    const float* __restrict__ Sout, const float* __restrict__ x,
    const float* __restrict__ n1w, const float* __restrict__ n1b,
    const float* __restrict__ n2w, const float* __restrict__ n2b,
    const float* __restrict__ W1w, const float* __restrict__ W1b,
    const float* __restrict__ W2w, const float* __restrict__ W2b,
    const float* __restrict__ Wtw, const float* __restrict__ Wtb,
    const float* __restrict__ W3w, const float* __restrict__ W3b,
    float* __restrict__ out) {
    __shared__ float tabc[96], tabs[96];
    __shared__ float srow[HROWS][18];
    __shared__ float tbuf[HROWS][96];
    __shared__ float hraw[HROWS][96];
    __shared__ float sH[HROWS][96];
    __shared__ float h2[HROWS][64];
    __shared__ float s3[HROWS][64];
    __shared__ float red[HROWS][2];
    __shared__ float wbuf[6240];
    int tid = threadIdx.x;
    int wave = tid >> 6, lane = tid & 63;
    int bn0 = blockIdx.x * HROWS;
    if (tid < 96) {
        double a = 6.283185307179586476925286766559 * (double)tid / 96.0;
        tabc[tid] = (float)cos(a);
        tabs[tid] = (float)sin(a);
    }
    for (int i = tid; i < HROWS * 96; i += 1024) {
        int g = i / 96, t = i - g * 96;
        int bn = bn0 + g;
        hraw[g][t] = x[(bn >> 8) * TN + t * NNODE + (bn & 255)];
    }
    if (tid < HROWS * 18) {
        int g = tid / 18, k = tid - g * 18;
        srow[g][k] = Sout[(bn0 + g) * 18 + k];
    }
    __syncthreads();
    for (int i = tid; i < HROWS * 96; i += 1024) {
        int g = i / 96, t = i - g * 96;
        int tm = t > 0 ? t - 1 : 0;
        int tp = t < SEQ - 1 ? t + 1 : SEQ - 1;
        tbuf[g][t] = (hraw[g][tm] + hraw[g][t] + hraw[g][tp]) * (1.0f / 3.0f);
    }
    __syncthreads();
    for (int i = tid; i < HROWS * 96; i += 1024) {
        int g = i / 96, t = i - g * 96;
        float acc = srow[g][0];   // Im(bin0) ignored by irfft
        #pragma unroll
        for (int c = 1; c < CFREQ; ++c) {
            int k = (c * t) % 96;
            acc += 2.0f * (srow[g][2 * c] * tabc[k] - srow[g][2 * c + 1] * tabs[k]);
        }
        hraw[g][t] = acc * 0.10206207261596575f;  // 1/sqrt(96)
    }
    __syncthreads();
    {
        float v = hraw[wave][lane] + ((lane < 32) ? hraw[wave][64 + lane] : 0.0f);
        #pragma unroll
        for (int off = 32; off > 0; off >>= 1) v += __shfl_down(v, off, 64);
        if (lane == 0) red[wave][0] = v * (1.0f / 96.0f);
    }
    __syncthreads();
    {
        float mu = red[wave][0];
        float d0 = hraw[wave][lane] - mu;
        float v = d0 * d0;
        if (lane < 32) { float d1 = hraw[wave][64 + lane] - mu; v += d1 * d1; }
        #pragma unroll
        for (int off = 32; off > 0; off >>= 1) v += __shfl_down(v, off, 64);
        if (lane == 0) red[wave][1] = v * (1.0f / 96.0f);
    }
    __syncthreads();
    for (int i = tid; i < HROWS * 96; i += 1024) {
        int g = i / 96, t = i - g * 96;
        int n = (bn0 + g) & 255;
        float xn = (hraw[g][t] - red[g][0]) / sqrtf(red[g][1] + 1e-5f) * n1w[n] + n1b[n];
        sH[g][t] = silu_f(xn);
    }
    for (int i = tid; i < HIDDEN * 96; i += 1024) {
        int rr = i / 96;
        wbuf[rr * 97 + (i - rr * 96)] = W1w[i];
    }
    __syncthreads();
    float v1;
    {
        float acc = W1b[lane];
        #pragma unroll 8
        for (int t = 0; t < 96; ++t) acc += sH[wave][t] * wbuf[lane * 97 + t];
        v1 = acc;
    }
    {
        float s = v1;
        #pragma unroll
        for (int off = 32; off > 0; off >>= 1) s += __shfl_down(s, off, 64);
        s = __shfl(s, 0, 64);
        float mu2 = s * (1.0f / 64.0f);
        float d = v1 - mu2;
        float vs = d * d;
        #pragma unroll
        for (int off = 32; off > 0; off >>= 1) vs += __shfl_down(vs, off, 64);
        vs = __shfl(vs, 0, 64);
        float var2 = vs * (1.0f / 64.0f);
        int n = (bn0 + wave) & 255;
        float xn = (v1 - mu2) / sqrtf(var2 + 1e-5f) * n2w[n] + n2b[n];
        h2[wave][lane] = silu_f(xn);
    }
    __syncthreads();   // wbuf(W1) reads + h2 writes done
    for (int i = tid; i < HIDDEN * HIDDEN; i += 1024) {
        wbuf[(i >> 6) * 65 + (i & 63)] = W2w[i];
    }
    __syncthreads();
    float v3;
    {
        float acc = W2b[lane];
        #pragma unroll 8
        for (int h = 0; h < 64; ++h) acc += h2[wave][h] * wbuf[lane * 65 + h];
        v3 = acc;
    }
    __syncthreads();   // wbuf(W2) reads done
    for (int i = tid; i < HIDDEN * 96; i += 1024) {
        int rr = i / 96;
        wbuf[rr * 97 + (i - rr * 96)] = Wtw[i];
    }
    __syncthreads();
    {
        float acc = Wtb[lane];
        #pragma unroll 8
        for (int t = 0; t < 96; ++t) acc += tbuf[wave][t] * wbuf[lane * 97 + t];
        s3[wave][lane] = v3 + acc;
    }
    __syncthreads();   // wbuf(Wt) reads + s3 writes done
    for (int i = tid; i < 96 * HIDDEN; i += 1024) {
        wbuf[(i >> 6) * 65 + (i & 63)] = W3w[i];
    }
    __syncthreads();
    for (int i = tid; i < HROWS * 96; i += 1024) {
        int g = i / 96, t = i - g * 96;
        float acc = W3b[t];
        #pragma unroll 8
        for (int h = 0; h < 64; ++h) acc += s3[g][h] * wbuf[t * 65 + h];
        out[(bn0 + g) * 96 + t] = acc;
    }
}

extern "C" void kernel_launch(void* const* d_in, const int* in_sizes, int n_in,
                              void* d_out, int out_size, void* d_ws, size_t ws_size,
                              hipStream_t stream) {
    const float* x     = (const float*)d_in[0];
    const float* approx= (const float*)d_in[1];
    const float* theta = (const float*)d_in[2];
    const float* frWr  = (const float*)d_in[3];
    const float* frWi  = (const float*)d_in[4];
    const float* eoWr  = (const float*)d_in[5];
    const float* eoWi  = (const float*)d_in[6];
    const float* femb  = (const float*)d_in[7];
    const float* n1w   = (const float*)d_in[8];
    const float* n1b   = (const float*)d_in[9];
    const float* n2w   = (const float*)d_in[10];
    const float* n2b   = (const float*)d_in[11];
    const float* W1w   = (const float*)d_in[12];
    const float* W1b   = (const float*)d_in[13];
    const float* W2w   = (const float*)d_in[14];
    const float* W2b   = (const float*)d_in[15];
    const float* Wtw   = (const float*)d_in[16];
    const float* Wtb   = (const float*)d_in[17];
    const float* W3w   = (const float*)d_in[18];
    const float* W3b   = (const float*)d_in[19];
    float* out = (float*)d_out;

    char* ws = (char*)d_ws;
    size_t off = 0;
    auto alloc = [&](size_t bytes) -> void* {
        void* p = ws + off;
        off = (off + bytes + 255) & ~(size_t)255;
        return p;
    };
    float* S     = (float*)alloc((size_t)BM * 2 * 4);
    int*   idx   = (int*)  alloc((size_t)BM * KNN * 4);
    float* dinv  = (float*)alloc((size_t)BM * 4);
    float* PS    = (float*)alloc((size_t)BM * 2 * 4);
    float* FE    = (float*)alloc((size_t)FEW * 2 * 4);
    float* Sout  = (float*)alloc((size_t)BM * 2 * 4);
    int2*  oc    = (int2*) alloc((size_t)BM * 8);
    int*   rev   = (int*)  alloc((size_t)BM * KNN * 4);
    float* zA    = (float*)alloc((size_t)BM * CFREQ * 2 * 4);
    float* zAw   = (float*)alloc((size_t)BM * CFREQ * 2 * 4);
    int*   cnt   = (int*)  alloc((size_t)BM * 4);
    int*   fptr  = (int*)  alloc((size_t)BM * 4);
    int*   gtotal= (int*)  alloc(256);

    // no memset: cnt+gtotal zeroed by prep; fptr seeded by scan_kernel
    prep_kernel<<<(BM + FEW + 255) / 256, 256, 0, stream>>>(x, S, cnt, femb, frWr, frWi, FE, gtotal);
    knn_kernel<<<dim3(MNODE / 4, BATCH), 256, 0, stream>>>(S, idx, cnt);
    scan_kernel<<<NBLK, 256, 0, stream>>>(cnt, S, dinv, PS, gtotal, oc, fptr);
    fill_kernel<<<(BM * KNN + 255) / 256, 256, 0, stream>>>(idx, fptr, rev);
    gather1_kernel<<<(BM * CFREQ + 255) / 256, 256, 0, stream>>>(idx, oc, rev, dinv, PS, zA, zAw);
    g2proj_kernel<<<BM / 4, 256, 0, stream>>>(idx, oc, rev, dinv, zA, zAw, S, FE,
                                              eoWr, eoWi, theta, approx, Sout);
    head_kernel<<<BATCH * NNODE / HROWS, 1024, 0, stream>>>(Sout, x, n1w, n1b, n2w, n2b,
                                                            W1w, W1b, W2w, W2b, Wtw, Wtb, W3w, W3b, out);
}

// Round 15
// 224.880 us; speedup vs baseline: 1.0816x; 1.0628x over previous
//
#include <hip/hip_runtime.h>
#include <math.h>
#include <float.h>

#define BATCH 16
#define SEQ 96
#define NNODE 256
#define CFREQ 9
#define MNODE (NNODE * CFREQ)      // 2304
#define BM (BATCH * MNODE)         // 36864
#define KNN 8
#define EMBED 128
#define HIDDEN 64
#define TN (SEQ * NNODE)           // 24576
#define KCAP 64
#define RCAP 64                    // fixed-stride reverse-list capacity
#define HROWS 16                   // head rows per block (1024 threads)
#define FEW (CFREQ * EMBED)        // 1152 fe outputs

__constant__ float COS16[16] = {
    1.0f, 0.9238795325112867f, 0.7071067811865476f, 0.3826834323650898f,
    0.0f, -0.3826834323650898f, -0.7071067811865476f, -0.9238795325112867f,
    -1.0f, -0.9238795325112867f, -0.7071067811865476f, -0.3826834323650898f,
    0.0f, 0.3826834323650898f, 0.7071067811865476f, 0.9238795325112867f};
__constant__ float SIN16[16] = {
    0.0f, 0.3826834323650898f, 0.7071067811865476f, 0.9238795325112867f,
    1.0f, 0.9238795325112867f, 0.7071067811865476f, 0.3826834323650898f,
    0.0f, -0.3826834323650898f, -0.7071067811865476f, -0.9238795325112867f,
    -1.0f, -0.9238795325112867f, -0.7071067811865476f, -0.3826834323650898f};

static __device__ __forceinline__ float silu_f(float x) {
    return x / (1.0f + expf(-x));
}

// degree-normalisation weight from final cnt (same expression as before)
static __device__ __forceinline__ float dinv_of(int c) {
    return 1.0f / sqrtf((float)(KNN + c) + 1e-8f);
}

// ranking value h = |fj|^2 - 2*(fi . fj) (monotone with d = sqi + h)
static __device__ __forceinline__ float rank_h(float2 fj, float xi2, float yi2) {
    float sqj = __fmaf_rn(fj.y, fj.y, __fmul_rn(fj.x, fj.x));
    return __fmaf_rn(xi2, fj.x, __fmaf_rn(yi2, fj.y, sqj));
}

// Fused: per-(b,n,c) thread computes trend inline (bit-exact expression) and
// the rfft16 bin; zeroes cnt and the overflow ticket. Extra blocks compute FE.
__global__ void __launch_bounds__(256) prep_kernel(
    const float* __restrict__ x, float* __restrict__ S, int* __restrict__ cnt,
    const float* __restrict__ femb, const float* __restrict__ Wr,
    const float* __restrict__ Wi, float* __restrict__ FE, int* __restrict__ ovfcnt) {
    int gid = blockIdx.x * 256 + threadIdx.x;
    if (gid < BM) {
        if (gid == 0) *ovfcnt = 0;
        cnt[gid] = 0;
        int b = gid / MNODE;
        int m = gid - b * MNODE;
        int n = m / CFREQ;
        int c = m - n * CFREQ;
        const float* xb = x + b * TN + n;
        float xv[17];
        #pragma unroll
        for (int t = 0; t < 17; ++t) xv[t] = xb[t * NNODE];
        float re = 0.0f, im = 0.0f;
        #pragma unroll
        for (int t = 0; t < 16; ++t) {
            int tm = t > 0 ? t - 1 : 0;
            float tr = (xv[tm] + xv[t] + xv[t + 1]) * (1.0f / 3.0f);
            float s = xv[t] - tr;
            int k = (c * t) & 15;
            re += s * COS16[k];
            im -= s * SIN16[k];
        }
        S[gid * 2 + 0] = re * 0.25f;
        S[gid * 2 + 1] = im * 0.25f;
    } else {
        int f = gid - BM;
        if (f < FEW) {
            int c = f / EMBED;
            int e = f - c * EMBED;
            float ar = 0.0f, ai = 0.0f;
            for (int k = 0; k < EMBED; ++k) {
                float fv = femb[c * EMBED + k];
                ar += fv * Wr[e * EMBED + k];
                ai += fv * Wi[e * EMBED + k];
            }
            FE[f * 2 + 0] = ar;
            FE[f * 2 + 1] = ai;
        }
    }
}

// One WAVE per row, 4 rows per 256-block. Exact top-8, and the reverse-edge
// build is fused here: on selecting neighbor j, the pre-existing
// atomicAdd(&cnt[gj]) now doubles as a slot ticket into j's fixed-stride
// reverse slab rev[gj*RCAP + pos]. pos >= RCAP (in-degree > 64, pathological)
// pushes (gj, gi) to the overflow list (sized BM*KNN = total edges, so the
// ticket can never overrun). This deletes the scan and fill kernels.
__global__ void __launch_bounds__(256, 8) knn_kernel(
    const float* __restrict__ S, int* __restrict__ idx, int* __restrict__ cnt,
    int* __restrict__ rev, int2* __restrict__ ovf, int* __restrict__ ovfcnt) {
    __shared__ float2 f[MNODE];                        // 18432 B
    __shared__ unsigned long long kbuf[4][KCAP];       // 2048 B -> total 20480 = 160K/8
    int b = blockIdx.y;
    int tid = threadIdx.x;
    for (int t = tid; t < MNODE; t += 256) {
        f[t] = make_float2(S[(b * MNODE + t) * 2 + 0], S[(b * MNODE + t) * 2 + 1]);
    }
    __syncthreads();
    int wave = tid >> 6, lane = tid & 63;
    int i = blockIdx.x * 4 + wave;
    float2 fi = f[i];
    float xi2 = __fmul_rn(-2.0f, fi.x), yi2 = __fmul_rn(-2.0f, fi.y);
    int lane_i = __builtin_amdgcn_readfirstlane(i & 63);
    int k_i    = __builtin_amdgcn_readfirstlane(i >> 6);

    float h[36];
    float mymin = FLT_MAX;
    #pragma unroll
    for (int k = 0; k < 36; ++k) {
        int j = lane + (k << 6);
        float hh = rank_h(f[j], xi2, yi2);
        if (k == k_i && lane == lane_i) hh = FLT_MAX;
        h[k] = hh;
        mymin = fminf(mymin, hh);
    }
    float g = mymin;
    g = fminf(g, __shfl_xor(g, 1, 64));
    g = fminf(g, __shfl_xor(g, 2, 64));
    g = fminf(g, __shfl_xor(g, 4, 64));
    float T = g;
    T = fmaxf(T, __shfl_xor(T, 8, 64));
    T = fmaxf(T, __shfl_xor(T, 16, 64));
    T = fmaxf(T, __shfl_xor(T, 32, 64));
    unsigned long long* mybuf = kbuf[wave];
    const unsigned long long lmask = (1ull << lane) - 1ull;
    int total = 0;
    #pragma unroll
    for (int k = 0; k < 36; ++k) {
        bool pred = h[k] <= T;
        unsigned long long mask = __ballot(pred);
        if (pred) {
            int pos = total + (int)__popcll(mask & lmask);
            if (pos < KCAP) {
                unsigned int bits = __float_as_uint(h[k]);
                if (bits == 0x80000000u) bits = 0u;
                unsigned int s = bits ^ (unsigned int)(((int)bits >> 31) | 0x80000000);
                mybuf[pos] = ((unsigned long long)s << 32) | (unsigned int)(lane + (k << 6));
            }
        }
        total += (int)__popcll(mask);
    }
    // no block barrier: kbuf[wave] is wave-private; same-wave DS ops in-order

    int gi = b * MNODE + i;
    if (total >= KNN && total <= KCAP) {
        int padded = (total + 7) & ~7;                 // <= KCAP (64) always
        if (lane < padded - total) mybuf[total + lane] = ~0ull;
        for (int p = lane; p < total; p += 64) {
            unsigned long long mykey = mybuf[p];
            int rank = 0;
            for (int q = 0; q < padded; q += 8) {
                const ulonglong2* bp = (const ulonglong2*)&mybuf[q];
                ulonglong2 a = bp[0], b2 = bp[1], c2 = bp[2], d2 = bp[3];
                rank += (int)(a.x  < mykey) + (int)(a.y  < mykey)
                      + (int)(b2.x < mykey) + (int)(b2.y < mykey)
                      + (int)(c2.x < mykey) + (int)(c2.y < mykey)
                      + (int)(d2.x < mykey) + (int)(d2.y < mykey);
            }
            if (rank < KNN) {
                int j = (int)(unsigned int)(mykey & 0xFFFFFFFFull);
                int gj = b * MNODE + j;
                idx[gi * KNN + rank] = j;
                int pos = atomicAdd(&cnt[gj], 1);
                if (pos < RCAP) {
                    rev[gj * RCAP + pos] = gi;
                } else {
                    int t = atomicAdd(ovfcnt, 1);
                    ovf[t] = make_int2(gj, gi);
                }
            }
        }
    } else {
        const unsigned long long SENT = ~0ull;
        unsigned long long k0 = SENT, k1 = SENT, k2 = SENT, k3 = SENT,
                           k4 = SENT, k5 = SENT, k6 = SENT, k7 = SENT;
        #pragma unroll
        for (int k = 0; k < 36; ++k) {
            unsigned int bits = __float_as_uint(h[k]);
            if (bits == 0x80000000u) bits = 0u;
            unsigned int s = bits ^ (unsigned int)(((int)bits >> 31) | 0x80000000);
            unsigned long long key = ((unsigned long long)s << 32) | (unsigned int)(lane + (k << 6));
            if (key < k7) {
                k7 = key;
                if (k7 < k6) { unsigned long long t = k6; k6 = k7; k7 = t; }
                if (k6 < k5) { unsigned long long t = k5; k5 = k6; k6 = t; }
                if (k5 < k4) { unsigned long long t = k4; k4 = k5; k5 = t; }
                if (k4 < k3) { unsigned long long t = k3; k3 = k4; k4 = t; }
                if (k3 < k2) { unsigned long long t = k2; k2 = k3; k3 = t; }
                if (k2 < k1) { unsigned long long t = k1; k1 = k2; k2 = t; }
                if (k1 < k0) { unsigned long long t = k0; k0 = k1; k1 = t; }
            }
        }
        unsigned long long mywin = 0;
        #pragma unroll
        for (int r = 0; r < KNN; ++r) {
            unsigned long long hh = k0;
            #pragma unroll
            for (int off = 32; off > 0; off >>= 1) {
                unsigned long long o = __shfl_xor(hh, off, 64);
                if (o < hh) hh = o;
            }
            if (lane == r) mywin = hh;
            if (k0 == hh) {
                k0 = k1; k1 = k2; k2 = k3; k3 = k4; k4 = k5; k5 = k6; k6 = k7; k7 = SENT;
            }
        }
        if (lane < KNN) {
            int j = (int)(unsigned int)(mywin & 0xFFFFFFFFull);
            int gj = b * MNODE + j;
            idx[gi * KNN + lane] = j;
            int pos = atomicAdd(&cnt[gj], 1);
            if (pos < RCAP) {
                rev[gj * RCAP + pos] = gi;
            } else {
                int t = atomicAdd(ovfcnt, 1);
                ovf[t] = make_int2(gj, gi);
            }
        }
    }
}

// zA[i][c] = 0.5*dinv[i] * sum over neighbors j (both directions) with j%9==c
// of dinv[j]*S[j]; 9 threads per row (one per c). dinv computed inline from
// final cnt (scan/PS pass deleted). Also emits zAw[i][c] = dinv[i]*zA[i][c].
// Overflow neighbors (cnt > RCAP) come from the ovf list (normally empty).
__global__ void __launch_bounds__(256) gather1_kernel(
    const int* __restrict__ idx, const int* __restrict__ cnt,
    const int* __restrict__ rev, const int2* __restrict__ ovf,
    const int* __restrict__ ovfcnt, const float* __restrict__ S,
    float* __restrict__ zA, float* __restrict__ zAw) {
    int gid = blockIdx.x * blockDim.x + threadIdx.x;
    if (gid >= BM * CFREQ) return;
    int gi = gid / CFREQ;
    int c = gid - gi * CFREQ;
    int b = gi / MNODE;
    float ax = 0.0f, ay = 0.0f;
    #pragma unroll
    for (int k = 0; k < KNN; ++k) {
        int gj = b * MNODE + idx[gi * KNN + k];
        bool m = (gj % CFREQ) == c;
        float dvj = dinv_of(cnt[gj]);
        float2 p = ((const float2*)S)[gj];
        ax += m ? dvj * p.x : 0.0f;
        ay += m ? dvj * p.y : 0.0f;
    }
    int cn = cnt[gi];
    int e = cn < RCAP ? cn : RCAP;
    for (int p_ = 0; p_ < e; ++p_) {
        int gk = rev[gi * RCAP + p_];
        bool m = (gk % CFREQ) == c;
        float dvk = dinv_of(cnt[gk]);
        float2 p = ((const float2*)S)[gk];
        ax += m ? dvk * p.x : 0.0f;
        ay += m ? dvk * p.y : 0.0f;
    }
    if (cn > RCAP) {
        int tot = *ovfcnt;
        for (int t = 0; t < tot; ++t) {
            int2 o = ovf[t];
            if (o.x == gi) {
                int gk = o.y;
                bool m = (gk % CFREQ) == c;
                float dvk = dinv_of(cnt[gk]);
                float2 p = ((const float2*)S)[gk];
                ax += m ? dvk * p.x : 0.0f;
                ay += m ? dvk * p.y : 0.0f;
            }
        }
    }
    float dv = dinv_of(cn);
    float s = dv * 0.5f;
    float zx = s * ax, zy = s * ay;
    zA[gid * 2 + 0] = zx;
    zA[gid * 2 + 1] = zy;
    zAw[gid * 2 + 0] = dv * zx;
    zAw[gid * 2 + 1] = dv * zy;
}

// Fused gather2 + rowproj: one WAVE per row.
//  Phase 1 (lanes 0..35): quad q=lane>>2 owns c=q; sub=lane&3 strides the
//    KNN + rev (+ ovf, pathological) neighbor lists 4-ways over zAw;
//    quad-reduce via shfl_xor(1,2); sub==0 combines with zA (Chebyshev fold)
//    and writes zf[c] to the wave's LDS slot. No barrier: same-wave DS ops
//    are in-order, writes precede reads in program order.
//  Phase 2 (all 64 lanes): rowproj from LDS zf (u = z.FE -> csilu -> eo).
__global__ void __launch_bounds__(256) g2proj_kernel(
    const int* __restrict__ idx, const int* __restrict__ cnt,
    const int* __restrict__ rev, const int2* __restrict__ ovf,
    const int* __restrict__ ovfcnt,
    const float* __restrict__ zA, const float* __restrict__ zAw,
    const float* __restrict__ S, const float* __restrict__ FE,
    const float* __restrict__ eoWr, const float* __restrict__ eoWi,
    const float* __restrict__ theta, const float* __restrict__ approx,
    float* __restrict__ Sout) {
    __shared__ float2 zfb[4][CFREQ];   // 288 B
    int wave = threadIdx.x >> 6;
    int lane = threadIdx.x & 63;
    int r = blockIdx.x * 4 + wave;
    if (r >= BM) return;
    float a0 = theta[0] * approx[0] + theta[1] * approx[3];
    float a1 = theta[0] * approx[1] + theta[1] * approx[4];
    float a2 = theta[0] * approx[2] + theta[1] * approx[5];
    float ca = a0 - a2, cb = -a1, cc = 2.0f * a2;
    int b = r / MNODE;
    int cn = cnt[r];
    if (lane < 36) {
        int c = lane >> 2, sub = lane & 3;
        float ax = 0.0f, ay = 0.0f;
        #pragma unroll
        for (int k = sub; k < KNN; k += 4) {
            int gj = b * MNODE + idx[r * KNN + k];
            float2 v = ((const float2*)zAw)[gj * CFREQ + c];
            ax += v.x;
            ay += v.y;
        }
        int e = cn < RCAP ? cn : RCAP;
        for (int p = sub; p < e; p += 4) {
            int gk = rev[r * RCAP + p];
            float2 v = ((const float2*)zAw)[gk * CFREQ + c];
            ax += v.x;
            ay += v.y;
        }
        if (cn > RCAP) {
            int tot = *ovfcnt;
            for (int t = sub; t < tot; t += 4) {
                int2 o = ovf[t];
                if (o.x == r) {
                    float2 v = ((const float2*)zAw)[o.y * CFREQ + c];
                    ax += v.x;
                    ay += v.y;
                }
            }
        }
        ax += __shfl_xor(ax, 1, 64);  ay += __shfl_xor(ay, 1, 64);
        ax += __shfl_xor(ax, 2, 64);  ay += __shfl_xor(ay, 2, 64);
        if (sub == 0) {
            float s = dinv_of(cn) * 0.5f;
            float2 za = ((const float2*)zA)[r * CFREQ + c];
            zfb[wave][c] = make_float2(cb * za.x + cc * (s * ax),
                                       cb * za.y + cc * (s * ay));
        }
    }
    // same-wave LDS ordering: ds_writes above issue before the ds_reads below
    int cr = r % CFREQ;
    float sr = S[r * 2 + 0], si = S[r * 2 + 1];
    int e1 = lane + 64;
    float ur0 = 0.0f, ui0 = 0.0f, ur1 = 0.0f, ui1 = 0.0f;
    #pragma unroll
    for (int c = 0; c < CFREQ; ++c) {
        float2 zf = zfb[wave][c];
        float zr = zf.x, zi = zf.y;
        if (c == cr) { zr += ca * sr; zi += ca * si; }
        float fr0 = FE[(c * EMBED + lane) * 2 + 0], fi0 = FE[(c * EMBED + lane) * 2 + 1];
        float fr1 = FE[(c * EMBED + e1) * 2 + 0],  fi1 = FE[(c * EMBED + e1) * 2 + 1];
        ur0 += zr * fr0 - zi * fi0;  ui0 += zr * fi0 + zi * fr0;
        ur1 += zr * fr1 - zi * fi1;  ui1 += zr * fi1 + zi * fr1;
    }
    float hr0 = silu_f(ur0), hi0 = silu_f(ui0);
    float hr1 = silu_f(ur1), hi1 = silu_f(ui1);
    float wr0 = eoWr[lane], wi0 = eoWi[lane], wr1 = eoWr[e1], wi1 = eoWi[e1];
    float p = hr0 * wr0 - hi0 * wi0 + hr1 * wr1 - hi1 * wi1;
    float q = hr0 * wi0 + hi0 * wr0 + hr1 * wi1 + hi1 * wr1;
    #pragma unroll
    for (int off = 32; off > 0; off >>= 1) {
        p += __shfl_down(p, off, 64);
        q += __shfl_down(q, off, 64);
    }
    if (lane == 0) {
        Sout[r * 2 + 0] = p;
        Sout[r * 2 + 1] = q;
    }
}

// per (b,n): irfft96 -> inorm+silu -> W1 -> inorm+silu -> W2 -> + trend_emb -> W3 -> out
// HROWS=16 rows per 1024-thread block. Trend recomputed inline from x
// (bit-exact expression), staged through hraw (overwritten by irfft).
__global__ void __launch_bounds__(1024) head_kernel(
    const float* __restrict__ Sout, const float* __restrict__ x,
    const float* __restrict__ n1w, const float* __restrict__ n1b,
    const float* __restrict__ n2w, const float* __restrict__ n2b,
    const float* __restrict__ W1w, const float* __restrict__ W1b,
    const float* __restrict__ W2w, const float* __restrict__ W2b,
    const float* __restrict__ Wtw, const float* __restrict__ Wtb,
    const float* __restrict__ W3w, const float* __restrict__ W3b,
    float* __restrict__ out) {
    __shared__ float tabc[96], tabs[96];
    __shared__ float srow[HROWS][18];
    __shared__ float tbuf[HROWS][96];
    __shared__ float hraw[HROWS][96];
    __shared__ float sH[HROWS][96];
    __shared__ float h2[HROWS][64];
    __shared__ float s3[HROWS][64];
    __shared__ float red[HROWS][2];
    __shared__ float wbuf[6240];
    int tid = threadIdx.x;
    int wave = tid >> 6, lane = tid & 63;
    int bn0 = blockIdx.x * HROWS;
    if (tid < 96) {
        double a = 6.283185307179586476925286766559 * (double)tid / 96.0;
        tabc[tid] = (float)cos(a);
        tabs[tid] = (float)sin(a);
    }
    for (int i = tid; i < HROWS * 96; i += 1024) {
        int g = i / 96, t = i - g * 96;
        int bn = bn0 + g;
        hraw[g][t] = x[(bn >> 8) * TN + t * NNODE + (bn & 255)];
    }
    if (tid < HROWS * 18) {
        int g = tid / 18, k = tid - g * 18;
        srow[g][k] = Sout[(bn0 + g) * 18 + k];
    }
    __syncthreads();
    for (int i = tid; i < HROWS * 96; i += 1024) {
        int g = i / 96, t = i - g * 96;
        int tm = t > 0 ? t - 1 : 0;
        int tp = t < SEQ - 1 ? t + 1 : SEQ - 1;
        tbuf[g][t] = (hraw[g][tm] + hraw[g][t] + hraw[g][tp]) * (1.0f / 3.0f);
    }
    __syncthreads();
    for (int i = tid; i < HROWS * 96; i += 1024) {
        int g = i / 96, t = i - g * 96;
        float acc = srow[g][0];   // Im(bin0) ignored by irfft
        #pragma unroll
        for (int c = 1; c < CFREQ; ++c) {
            int k = (c * t) % 96;
            acc += 2.0f * (srow[g][2 * c] * tabc[k] - srow[g][2 * c + 1] * tabs[k]);
        }
        hraw[g][t] = acc * 0.10206207261596575f;  // 1/sqrt(96)
    }
    __syncthreads();
    {
        float v = hraw[wave][lane] + ((lane < 32) ? hraw[wave][64 + lane] : 0.0f);
        #pragma unroll
        for (int off = 32; off > 0; off >>= 1) v += __shfl_down(v, off, 64);
        if (lane == 0) red[wave][0] = v * (1.0f / 96.0f);
    }
    __syncthreads();
    {
        float mu = red[wave][0];
        float d0 = hraw[wave][lane] - mu;
        float v = d0 * d0;
        if (lane < 32) { float d1 = hraw[wave][64 + lane] - mu; v += d1 * d1; }
        #pragma unroll
        for (int off = 32; off > 0; off >>= 1) v += __shfl_down(v, off, 64);
        if (lane == 0) red[wave][1] = v * (1.0f / 96.0f);
    }
    __syncthreads();
    for (int i = tid; i < HROWS * 96; i += 1024) {
        int g = i / 96, t = i - g * 96;
        int n = (bn0 + g) & 255;
        float xn = (hraw[g][t] - red[g][0]) / sqrtf(red[g][1] + 1e-5f) * n1w[n] + n1b[n];
        sH[g][t] = silu_f(xn);
    }
    for (int i = tid; i < HIDDEN * 96; i += 1024) {
        int rr = i / 96;
        wbuf[rr * 97 + (i - rr * 96)] = W1w[i];
    }
    __syncthreads();
    float v1;
    {
        float acc = W1b[lane];
        #pragma unroll 8
        for (int t = 0; t < 96; ++t) acc += sH[wave][t] * wbuf[lane * 97 + t];
        v1 = acc;
    }
    {
        float s = v1;
        #pragma unroll
        for (int off = 32; off > 0; off >>= 1) s += __shfl_down(s, off, 64);
        s = __shfl(s, 0, 64);
        float mu2 = s * (1.0f / 64.0f);
        float d = v1 - mu2;
        float vs = d * d;
        #pragma unroll
        for (int off = 32; off > 0; off >>= 1) vs += __shfl_down(vs, off, 64);
        vs = __shfl(vs, 0, 64);
        float var2 = vs * (1.0f / 64.0f);
        int n = (bn0 + wave) & 255;
        float xn = (v1 - mu2) / sqrtf(var2 + 1e-5f) * n2w[n] + n2b[n];
        h2[wave][lane] = silu_f(xn);
    }
    __syncthreads();   // wbuf(W1) reads + h2 writes done
    for (int i = tid; i < HIDDEN * HIDDEN; i += 1024) {
        wbuf[(i >> 6) * 65 + (i & 63)] = W2w[i];
    }
    __syncthreads();
    float v3;
    {
        float acc = W2b[lane];
        #pragma unroll 8
        for (int h = 0; h < 64; ++h) acc += h2[wave][h] * wbuf[lane * 65 + h];
        v3 = acc;
    }
    __syncthreads();   // wbuf(W2) reads done
    for (int i = tid; i < HIDDEN * 96; i += 1024) {
        int rr = i / 96;
        wbuf[rr * 97 + (i - rr * 96)] = Wtw[i];
    }
    __syncthreads();
    {
        float acc = Wtb[lane];
        #pragma unroll 8
        for (int t = 0; t < 96; ++t) acc += tbuf[wave][t] * wbuf[lane * 97 + t];
        s3[wave][lane] = v3 + acc;
    }
    __syncthreads();   // wbuf(Wt) reads + s3 writes done
    for (int i = tid; i < 96 * HIDDEN; i += 1024) {
        wbuf[(i >> 6) * 65 + (i & 63)] = W3w[i];
    }
    __syncthreads();
    for (int i = tid; i < HROWS * 96; i += 1024) {
        int g = i / 96, t = i - g * 96;
        float acc = W3b[t];
        #pragma unroll 8
        for (int h = 0; h < 64; ++h) acc += s3[g][h] * wbuf[t * 65 + h];
        out[(bn0 + g) * 96 + t] = acc;
    }
}

extern "C" void kernel_launch(void* const* d_in, const int* in_sizes, int n_in,
                              void* d_out, int out_size, void* d_ws, size_t ws_size,
                              hipStream_t stream) {
    const float* x     = (const float*)d_in[0];
    const float* approx= (const float*)d_in[1];
    const float* theta = (const float*)d_in[2];
    const float* frWr  = (const float*)d_in[3];
    const float* frWi  = (const float*)d_in[4];
    const float* eoWr  = (const float*)d_in[5];
    const float* eoWi  = (const float*)d_in[6];
    const float* femb  = (const float*)d_in[7];
    const float* n1w   = (const float*)d_in[8];
    const float* n1b   = (const float*)d_in[9];
    const float* n2w   = (const float*)d_in[10];
    const float* n2b   = (const float*)d_in[11];
    const float* W1w   = (const float*)d_in[12];
    const float* W1b   = (const float*)d_in[13];
    const float* W2w   = (const float*)d_in[14];
    const float* W2b   = (const float*)d_in[15];
    const float* Wtw   = (const float*)d_in[16];
    const float* Wtb   = (const float*)d_in[17];
    const float* W3w   = (const float*)d_in[18];
    const float* W3b   = (const float*)d_in[19];
    float* out = (float*)d_out;

    char* ws = (char*)d_ws;
    size_t off = 0;
    auto alloc = [&](size_t bytes) -> void* {
        void* p = ws + off;
        off = (off + bytes + 255) & ~(size_t)255;
        return p;
    };
    float* S     = (float*)alloc((size_t)BM * 2 * 4);
    int*   idx   = (int*)  alloc((size_t)BM * KNN * 4);
    float* FE    = (float*)alloc((size_t)FEW * 2 * 4);
    float* Sout  = (float*)alloc((size_t)BM * 2 * 4);
    int*   rev   = (int*)  alloc((size_t)BM * RCAP * 4);
    float* zA    = (float*)alloc((size_t)BM * CFREQ * 2 * 4);
    float* zAw   = (float*)alloc((size_t)BM * CFREQ * 2 * 4);
    int*   cnt   = (int*)  alloc((size_t)BM * 4);
    int2*  ovf   = (int2*) alloc((size_t)BM * KNN * 8);
    int*   ovfcnt= (int*)  alloc(256);

    // no memset: cnt+ovfcnt zeroed by prep; rev slots gated by cnt
    prep_kernel<<<(BM + FEW + 255) / 256, 256, 0, stream>>>(x, S, cnt, femb, frWr, frWi, FE, ovfcnt);
    knn_kernel<<<dim3(MNODE / 4, BATCH), 256, 0, stream>>>(S, idx, cnt, rev, ovf, ovfcnt);
    gather1_kernel<<<(BM * CFREQ + 255) / 256, 256, 0, stream>>>(idx, cnt, rev, ovf, ovfcnt, S, zA, zAw);
    g2proj_kernel<<<BM / 4, 256, 0, stream>>>(idx, cnt, rev, ovf, ovfcnt, zA, zAw, S, FE,
                                              eoWr, eoWi, theta, approx, Sout);
    head_kernel<<<BATCH * NNODE / HROWS, 1024, 0, stream>>>(Sout, x, n1w, n1b, n2w, n2b,
                                                            W1w, W1b, W2w, W2b, Wtw, Wtb, W3w, W3b, out);
}